// Round 4
// baseline (504.601 us; speedup 1.0000x reference)
//
#include <hip/hip_runtime.h>

// (E,B,C,H,W) = (3,8,10,512,512), HIDDEN=256
#define HWQ   262144      // H*W
#define CHW   2621440     // C*H*W
#define BCHW  20971520    // B*C*H*W
#define NTOT  2097152     // B*H*W

#define NBLOCKS   768     // 3 resident blocks per CU, exactly
#define NBLKITER  8192    // NTOT / 256 tokens-per-block-iter
#define BITERS    11      // ceil(8192/768); guard g < NBLKITER

typedef __attribute__((ext_vector_type(8))) short short8;  // 8 bf16 (4 VGPRs)
typedef __attribute__((ext_vector_type(4))) float f32x4;

union Frag { uint u[4]; uint4 u4; short8 s; };   // 16B type-pun (union: OK in HIP)

// f32 -> bf16 (RNE), pure C bit-trick (no inline asm — inline-asm cvt_pk was
// the round-1/2 container killer; compiler emits good code for this).
__device__ __forceinline__ uint bf16w(float x) {
    const uint u = __float_as_uint(x);
    return (u + 0x7FFFu + ((u >> 16) & 1u)) >> 16;   // bf16 in low 16 bits
}

// 3-limb split of an f32 pair into packed bf16 words (lo16 = a, hi16 = b).
// v = hi + mid + lo with residual ~2^-25 * |v| (hi/mid subtractions exact).
__device__ __forceinline__ void split_pair(float a, float b,
                                           uint& h, uint& m, uint& l) {
    const uint ha = bf16w(a), hb = bf16w(b);
    h = ha | (hb << 16);
    const float fa = __uint_as_float(ha << 16);
    const float fb = __uint_as_float(hb << 16);
    const float ra = a - fa, rb = b - fb;
    const uint ma = bf16w(ra), mb = bf16w(rb);
    m = ma | (mb << 16);
    const float ga = __uint_as_float(ma << 16);
    const float gb = __uint_as_float(mb << 16);
    l = bf16w(ra - ga) | (bf16w(rb - gb) << 16);
}

// One fused kernel, no d_ws (prior session: d_ws writes corrupt harness state).
// Per block: stage w1(+b1 @ k=30) once into LDS as bf16x3-limb MFMA B-fragments,
// then each wave independently processes 32 tokens/iter:
//   gather x (30 planes, k=30 -> 1.0 bias, k=31 -> 0) -> 3-limb A-frags
//   -> 16 hidden-tiles x [6 limb-product MFMAs 16x16x32] -> relu -> h@w2 in fp32
//   -> 16-lane butterfly reduce (ALL lanes get full logits) -> per-lane argmax
//   -> 2-bit-packed sel + one shuffle -> gather-write selected expert's 10 planes.
// LDS = Bfrag 49,152 + W2s 3,072 = 52,224 B  ->  3 blocks/CU (was 55,296 -> 2).
__global__ __launch_bounds__(512, 6)
void mlp_select_mfma(const float* __restrict__ inputs,
                     const float* __restrict__ w1,
                     const float* __restrict__ b1,
                     const float* __restrict__ w2,
                     const float* __restrict__ b2,
                     float* __restrict__ out0,
                     float* __restrict__ out1) {
    __shared__ uint4 Bfrag[16 * 3 * 64];   // 49,152 B: [ht][limb][lane] 16B frags
    __shared__ float W2s[768];             // w2 copy (256x3)

    const int tid = threadIdx.x;

    // ---- one-time staging: w1/b1 -> limb B-fragments; w2 -> LDS ----
    for (int idx = tid; idx < 16 * 64; idx += 512) {
        const int ht = idx >> 6, ln = idx & 63;
        const int col = (ht << 4) | (ln & 15);     // hidden unit (B col = lane&15)
        const int kbs = (ln >> 4) << 3;            // k-group base (same conv as A)
        Frag fh, fm, fl;
        #pragma unroll
        for (int jj = 0; jj < 4; ++jj) {
            const int k0 = kbs + 2 * jj, k1 = k0 + 1;
            const float a = (k0 < 30) ? w1[k0 * 256 + col]
                                      : ((k0 == 30) ? b1[col] : 0.f);
            const float b = (k1 < 30) ? w1[k1 * 256 + col]
                                      : ((k1 == 30) ? b1[col] : 0.f);
            split_pair(a, b, fh.u[jj], fm.u[jj], fl.u[jj]);
        }
        const int base = ht * 3 * 64 + ln;
        Bfrag[base]       = fh.u4;
        Bfrag[base + 64]  = fm.u4;
        Bfrag[base + 128] = fl.u4;
    }
    for (int i = tid; i < 768; i += 512) W2s[i] = w2[i];
    __syncthreads();

    const int lane = tid & 63;
    const int wid  = tid >> 6;
    const int l15  = lane & 15;
    const int lg   = lane >> 4;
    const int kb   = lg << 3;

    // per-lane byte offsets of the 8 k-planes this lane loads (A-frag k-slice)
    uint koff[8];
    #pragma unroll
    for (int j = 0; j < 8; ++j) {
        const int k = kb + j;
        const int e = (k >= 20) ? 2 : ((k >= 10) ? 1 : 0);
        const int c = k - e * 10;
        koff[j] = (k < 30) ? (uint)((e * BCHW + c * HWQ) * 4) : 0u;  // k>=30: dummy
    }
    // b2 folded into acc init: each of 16 butterfly lanes contributes b2/16,
    // summing back to exactly-one b2 (error class same as the limb residual).
    const float i20 = b2[0] * 0.0625f, i21 = b2[1] * 0.0625f, i22 = b2[2] * 0.0625f;
    const char* ib = (const char*)inputs;
    char* ob = (char*)out0;

    #pragma unroll 1
    for (int it = 0; it < BITERS; ++it) {
        const int g = it * NBLOCKS + (int)blockIdx.x;   // global block-iter
        if (g >= NBLKITER) break;                        // 97% full coverage
        const int n0 = g * 256 + wid * 32;               // wave's 32 tokens
        // 32-token runs never cross a b (2^18) boundary -> b,hw0 uniform per wave
        const uint sbase = (uint)((n0 >> 18) * CHW + (n0 & (HWQ - 1))) * 4u;

        // ---- gather + 3-limb split -> A fragments for 2 16-token tiles ----
        short8 Ah[2], Am[2], Al[2];
        #pragma unroll
        for (int t = 0; t < 2; ++t) {
            const uint vb = sbase + (uint)((t * 16 + l15) * 4);  // A row = lane&15
            float xv[8];
            #pragma unroll
            for (int j = 0; j < 8; ++j)
                xv[j] = *(const float*)(ib + (size_t)(vb + koff[j]));
            if (kb == 24) { xv[6] = 1.f; xv[7] = 0.f; }  // k=30 -> bias 1.0, k=31 -> 0
            Frag ch_, cm_, cl_;
            #pragma unroll
            for (int jj = 0; jj < 4; ++jj)
                split_pair(xv[2 * jj], xv[2 * jj + 1],
                           ch_.u[jj], cm_.u[jj], cl_.u[jj]);
            Ah[t] = ch_.s; Am[t] = cm_.s; Al[t] = cl_.s;
        }

        float lacc[2][4][3];
        #pragma unroll
        for (int t = 0; t < 2; ++t)
            #pragma unroll
            for (int r = 0; r < 4; ++r) {
                lacc[t][r][0] = i20; lacc[t][r][1] = i21; lacc[t][r][2] = i22;
            }

        // ---- 16 hidden-tiles: 6 limb-product MFMAs each (small terms first) ----
        #pragma unroll 4
        for (int ht = 0; ht < 16; ++ht) {
            const uint4* bp = &Bfrag[ht * 3 * 64 + lane];
            Frag bh, bm, bl;
            bh.u4 = bp[0]; bm.u4 = bp[64]; bl.u4 = bp[128];
            const int wcol = ((ht << 4) | l15) * 3;
            const float w20 = W2s[wcol], w21 = W2s[wcol + 1], w22 = W2s[wcol + 2];
            #pragma unroll
            for (int t = 0; t < 2; ++t) {
                f32x4 D = {0.f, 0.f, 0.f, 0.f};
                D = __builtin_amdgcn_mfma_f32_16x16x32_bf16(Al[t], bh.s, D, 0, 0, 0);
                D = __builtin_amdgcn_mfma_f32_16x16x32_bf16(Ah[t], bl.s, D, 0, 0, 0);
                D = __builtin_amdgcn_mfma_f32_16x16x32_bf16(Am[t], bm.s, D, 0, 0, 0);
                D = __builtin_amdgcn_mfma_f32_16x16x32_bf16(Am[t], bh.s, D, 0, 0, 0);
                D = __builtin_amdgcn_mfma_f32_16x16x32_bf16(Ah[t], bm.s, D, 0, 0, 0);
                D = __builtin_amdgcn_mfma_f32_16x16x32_bf16(Ah[t], bh.s, D, 0, 0, 0);
                #pragma unroll
                for (int r = 0; r < 4; ++r) {     // D: token = lg*4+r, hid = ht*16+l15
                    const float hre = fmaxf(D[r], 0.f);
                    lacc[t][r][0] = fmaf(hre, w20, lacc[t][r][0]);
                    lacc[t][r][1] = fmaf(hre, w21, lacc[t][r][1]);
                    lacc[t][r][2] = fmaf(hre, w22, lacc[t][r][2]);
                }
            }
        }

        // ---- butterfly-reduce over the 16 hidden-lanes: ALL lanes get sums ----
        #pragma unroll
        for (int t = 0; t < 2; ++t)
            #pragma unroll
            for (int r = 0; r < 4; ++r)
                #pragma unroll
                for (int e = 0; e < 3; ++e) {
                    float v = lacc[t][r][e];
                    v += __shfl_xor(v, 1);
                    v += __shfl_xor(v, 2);
                    v += __shfl_xor(v, 4);
                    v += __shfl_xor(v, 8);
                    lacc[t][r][e] = v;
                }

        // ---- per-lane argmax of this lg-group's 8 tokens, 2-bit packed ----
        uint selpk = 0;
        #pragma unroll
        for (int t = 0; t < 2; ++t)
            #pragma unroll
            for (int r = 0; r < 4; ++r) {
                const float L0 = lacc[t][r][0];
                const float L1 = lacc[t][r][1];
                const float L2 = lacc[t][r][2];
                int sel = 0; float best = L0;
                if (L1 > best) { best = L1; sel = 1; }
                if (L2 > best) { sel = 2; }
                selpk |= (uint)sel << ((t * 4 + r) * 2);
            }

        // route: token tt = t<<4 | lg'<<2 | r  lives in lanes with lg = lg'
        const int tt  = lane & 31;
        const int src = (((tt >> 2) & 3) << 4) | l15;        // same l15: permutation
        const uint pk = (uint)__shfl((int)selpk, src);
        const int sel = (int)((pk >> ((((tt >> 4) << 2) | (tt & 3)) * 2)) & 3u);

        // ---- gather-write selected expert's 10 planes ----
        const uint obase = sbase + (uint)(tt * 4);
        const uint ioff  = obase + (uint)sel * (uint)(BCHW * 4);
        const int chalf  = lane >> 5;          // lanes 0-31: c=0..4, 32-63: c=5..9
        #pragma unroll
        for (int cc = 0; cc < 5; ++cc) {
            const uint cofs = (uint)((chalf * 5 + cc) * (HWQ * 4));
            const float v = *(const float*)(ib + (size_t)(ioff + cofs));
            *(float*)(ob + (size_t)(obase + cofs)) = v;
        }
        if (lane < 32) out1[n0 + tt] = (float)sel;
    }
}

extern "C" void kernel_launch(void* const* d_in, const int* in_sizes, int n_in,
                              void* d_out, int out_size, void* d_ws, size_t ws_size,
                              hipStream_t stream) {
    const float* inputs = (const float*)d_in[0];   // (3,8,10,512,512)
    const float* w1     = (const float*)d_in[1];   // (30,256)
    const float* b1     = (const float*)d_in[2];   // (256,)
    const float* w2     = (const float*)d_in[3];   // (256,3)
    const float* b2     = (const float*)d_in[4];   // (3,)

    float* out0 = (float*)d_out;           // (8,10,512,512)
    float* out1 = out0 + BCHW;             // (8,512,512) selections as float

    mlp_select_mfma<<<NBLOCKS, 512, 0, stream>>>(
        inputs, w1, b1, w2, b2, out0, out1);
}

// Round 5
// 493.837 us; speedup vs baseline: 1.0218x; 1.0218x over previous
//
#include <hip/hip_runtime.h>

// (E,B,C,H,W) = (3,8,10,512,512), HIDDEN=256
#define HWQ   262144      // H*W
#define CHW   2621440     // C*H*W
#define BCHW  20971520    // B*C*H*W
#define NTOT  2097152     // B*H*W

#define NBLOCKS   768     // 3 resident blocks per CU, exactly
#define NBLKITER  8192    // NTOT / 256 tokens-per-block-iter
#define BITERS    11      // ceil(8192/768); guard g < NBLKITER

typedef __attribute__((ext_vector_type(8))) short short8;  // 8 bf16 (4 VGPRs)
typedef __attribute__((ext_vector_type(4))) float f32x4;
typedef __attribute__((ext_vector_type(2))) float v2f;     // packed fp32 pair

union Frag { uint u[4]; uint4 u4; short8 s; };   // 16B type-pun (union: OK in HIP)

// f32 -> bf16 (RNE), pure C bit-trick (no inline asm — inline-asm cvt_pk was
// the round-1/2 container killer; compiler emits good code for this).
__device__ __forceinline__ uint bf16w(float x) {
    const uint u = __float_as_uint(x);
    return (u + 0x7FFFu + ((u >> 16) & 1u)) >> 16;   // bf16 in low 16 bits
}

// 3-limb split of an f32 pair into packed bf16 words (lo16 = a, hi16 = b).
// v = hi + mid + lo with residual ~2^-25 * |v| (hi/mid subtractions exact).
__device__ __forceinline__ void split_pair(float a, float b,
                                           uint& h, uint& m, uint& l) {
    const uint ha = bf16w(a), hb = bf16w(b);
    h = ha | (hb << 16);
    const float fa = __uint_as_float(ha << 16);
    const float fb = __uint_as_float(hb << 16);
    const float ra = a - fa, rb = b - fb;
    const uint ma = bf16w(ra), mb = bf16w(rb);
    m = ma | (mb << 16);
    const float ga = __uint_as_float(ma << 16);
    const float gb = __uint_as_float(mb << 16);
    l = bf16w(ra - ga) | (bf16w(rb - gb) << 16);
}

// One fused kernel, no d_ws (prior session: d_ws writes corrupt harness state).
// Per block: stage w1(+b1 @ k=30) once into LDS as bf16x3-limb MFMA B-fragments,
// then each wave independently processes 32 tokens/iter:
//   gather x -> 3-limb A-frags -> 16 hidden-tiles x [6 limb MFMAs 16x16x32]
//   -> packed relu + h@w2 (v_pk_fma_f32 over the t-pair) -> butterfly reduce
//   -> per-lane argmax (2-bit packed) + one shuffle -> gather-write 10 planes.
// LDS = 49,152 + 3,072 = 52,224 B -> 3 blocks/CU (6 waves/SIMD).
// NOTE: plain launch_bounds — the (512,6) variant made the allocator squeeze
// to 40 VGPR and SPILL (round 4: +67 MB scratch writes, +245 MB fetch).
__global__ __launch_bounds__(512)
void mlp_select_mfma(const float* __restrict__ inputs,
                     const float* __restrict__ w1,
                     const float* __restrict__ b1,
                     const float* __restrict__ w2,
                     const float* __restrict__ b2,
                     float* __restrict__ out0,
                     float* __restrict__ out1) {
    __shared__ uint4 Bfrag[16 * 3 * 64];   // 49,152 B: [ht][limb][lane] 16B frags
    __shared__ float W2s[768];             // w2 copy (256x3)

    const int tid = threadIdx.x;

    // ---- one-time staging: w1/b1 -> limb B-fragments; w2 -> LDS ----
    for (int idx = tid; idx < 16 * 64; idx += 512) {
        const int ht = idx >> 6, ln = idx & 63;
        const int col = (ht << 4) | (ln & 15);     // hidden unit (B col = lane&15)
        const int kbs = (ln >> 4) << 3;            // k-group base (same conv as A)
        Frag fh, fm, fl;
        #pragma unroll
        for (int jj = 0; jj < 4; ++jj) {
            const int k0 = kbs + 2 * jj, k1 = k0 + 1;
            const float a = (k0 < 30) ? w1[k0 * 256 + col]
                                      : ((k0 == 30) ? b1[col] : 0.f);
            const float b = (k1 < 30) ? w1[k1 * 256 + col]
                                      : ((k1 == 30) ? b1[col] : 0.f);
            split_pair(a, b, fh.u[jj], fm.u[jj], fl.u[jj]);
        }
        const int base = ht * 3 * 64 + ln;
        Bfrag[base]       = fh.u4;
        Bfrag[base + 64]  = fm.u4;
        Bfrag[base + 128] = fl.u4;
    }
    for (int i = tid; i < 768; i += 512) W2s[i] = w2[i];
    __syncthreads();

    const int lane = tid & 63;
    const int wid  = tid >> 6;
    const int l15  = lane & 15;
    const int lg   = lane >> 4;
    const int kb   = lg << 3;

    // per-lane byte offsets of the 8 k-planes this lane loads (A-frag k-slice)
    uint koff[8];
    #pragma unroll
    for (int j = 0; j < 8; ++j) {
        const int k = kb + j;
        const int e = (k >= 20) ? 2 : ((k >= 10) ? 1 : 0);
        const int c = k - e * 10;
        koff[j] = (k < 30) ? (uint)((e * BCHW + c * HWQ) * 4) : 0u;  // k>=30: dummy
    }
    // b2 folded into acc init: each of 16 butterfly lanes contributes b2/16,
    // summing back to exactly-one b2 (error class same as the limb residual).
    const float i20 = b2[0] * 0.0625f, i21 = b2[1] * 0.0625f, i22 = b2[2] * 0.0625f;
    const char* ib = (const char*)inputs;
    char* ob = (char*)out0;

    #pragma unroll 1
    for (int it = 0; it < BITERS; ++it) {
        const int g = it * NBLOCKS + (int)blockIdx.x;   // global block-iter
        if (g >= NBLKITER) break;                        // 97% full coverage
        const int n0 = g * 256 + wid * 32;               // wave's 32 tokens
        // 32-token runs never cross a b (2^18) boundary -> b,hw0 uniform per wave
        const uint sbase = (uint)((n0 >> 18) * CHW + (n0 & (HWQ - 1))) * 4u;

        // ---- gather + 3-limb split -> A fragments for 2 16-token tiles ----
        short8 Ah[2], Am[2], Al[2];
        #pragma unroll
        for (int t = 0; t < 2; ++t) {
            const uint vb = sbase + (uint)((t * 16 + l15) * 4);  // A row = lane&15
            float xv[8];
            #pragma unroll
            for (int j = 0; j < 8; ++j)
                xv[j] = *(const float*)(ib + (size_t)(vb + koff[j]));
            if (kb == 24) { xv[6] = 1.f; xv[7] = 0.f; }  // k=30 -> bias 1.0, k=31 -> 0
            Frag ch_, cm_, cl_;
            #pragma unroll
            for (int jj = 0; jj < 4; ++jj)
                split_pair(xv[2 * jj], xv[2 * jj + 1],
                           ch_.u[jj], cm_.u[jj], cl_.u[jj]);
            Ah[t] = ch_.s; Am[t] = cm_.s; Al[t] = cl_.s;
        }

        // packed logit accumulators: element .x = token-tile t=0, .y = t=1
        v2f lacc[4][3];
        #pragma unroll
        for (int r = 0; r < 4; ++r) {
            lacc[r][0] = (v2f){i20, i20};
            lacc[r][1] = (v2f){i21, i21};
            lacc[r][2] = (v2f){i22, i22};
        }

        // ---- 16 hidden-tiles: 6 limb-product MFMAs each (small terms first),
        //      then packed relu + w2-fma epilogue (v_pk_* over the t-pair) ----
        #pragma unroll 4
        for (int ht = 0; ht < 16; ++ht) {
            const uint4* bp = &Bfrag[ht * 3 * 64 + lane];
            Frag bh, bm, bl;
            bh.u4 = bp[0]; bm.u4 = bp[64]; bl.u4 = bp[128];
            const int wcol = ((ht << 4) | l15) * 3;
            const float w20 = W2s[wcol], w21 = W2s[wcol + 1], w22 = W2s[wcol + 2];
            f32x4 Dt[2];
            #pragma unroll
            for (int t = 0; t < 2; ++t) {
                f32x4 D = {0.f, 0.f, 0.f, 0.f};
                D = __builtin_amdgcn_mfma_f32_16x16x32_bf16(Al[t], bh.s, D, 0, 0, 0);
                D = __builtin_amdgcn_mfma_f32_16x16x32_bf16(Ah[t], bl.s, D, 0, 0, 0);
                D = __builtin_amdgcn_mfma_f32_16x16x32_bf16(Am[t], bm.s, D, 0, 0, 0);
                D = __builtin_amdgcn_mfma_f32_16x16x32_bf16(Am[t], bh.s, D, 0, 0, 0);
                D = __builtin_amdgcn_mfma_f32_16x16x32_bf16(Ah[t], bm.s, D, 0, 0, 0);
                D = __builtin_amdgcn_mfma_f32_16x16x32_bf16(Ah[t], bh.s, D, 0, 0, 0);
                Dt[t] = D;
            }
            #pragma unroll
            for (int r = 0; r < 4; ++r) {     // D: token = lg*4+r (per tile), hid = ht*16+l15
                v2f h2 = {Dt[0][r], Dt[1][r]};
                h2 = __builtin_elementwise_max(h2, (v2f){0.f, 0.f});
                lacc[r][0] = __builtin_elementwise_fma(h2, (v2f){w20, w20}, lacc[r][0]);
                lacc[r][1] = __builtin_elementwise_fma(h2, (v2f){w21, w21}, lacc[r][1]);
                lacc[r][2] = __builtin_elementwise_fma(h2, (v2f){w22, w22}, lacc[r][2]);
            }
        }

        // ---- butterfly-reduce over the 16 hidden-lanes: ALL lanes get sums ----
        #pragma unroll
        for (int r = 0; r < 4; ++r)
            #pragma unroll
            for (int e = 0; e < 3; ++e) {
                v2f v = lacc[r][e];
                #pragma unroll
                for (int s = 1; s <= 8; s <<= 1) {
                    v2f o;
                    o.x = __shfl_xor(v.x, s);
                    o.y = __shfl_xor(v.y, s);
                    v += o;                                  // v_pk_add_f32
                }
                lacc[r][e] = v;
            }

        // ---- per-lane argmax of this lg-group's 8 tokens, 2-bit packed ----
        uint selpk = 0;
        #pragma unroll
        for (int t = 0; t < 2; ++t)
            #pragma unroll
            for (int r = 0; r < 4; ++r) {
                const float L0 = (t == 0) ? lacc[r][0].x : lacc[r][0].y;
                const float L1 = (t == 0) ? lacc[r][1].x : lacc[r][1].y;
                const float L2 = (t == 0) ? lacc[r][2].x : lacc[r][2].y;
                int sel = 0; float best = L0;
                if (L1 > best) { best = L1; sel = 1; }
                if (L2 > best) { sel = 2; }
                selpk |= (uint)sel << ((t * 4 + r) * 2);
            }

        // route: token tt = t<<4 | lg'<<2 | r  lives in lanes with lg = lg'
        const int tt  = lane & 31;
        const int src = (((tt >> 2) & 3) << 4) | l15;        // same l15: permutation
        const uint pk = (uint)__shfl((int)selpk, src);
        const int sel = (int)((pk >> ((((tt >> 4) << 2) | (tt & 3)) * 2)) & 3u);

        // ---- gather-write selected expert's 10 planes ----
        const uint obase = sbase + (uint)(tt * 4);
        const uint ioff  = obase + (uint)sel * (uint)(BCHW * 4);
        const int chalf  = lane >> 5;          // lanes 0-31: c=0..4, 32-63: c=5..9
        #pragma unroll
        for (int cc = 0; cc < 5; ++cc) {
            const uint cofs = (uint)((chalf * 5 + cc) * (HWQ * 4));
            const float v = *(const float*)(ib + (size_t)(ioff + cofs));
            *(float*)(ob + (size_t)(obase + cofs)) = v;
        }
        if (lane < 32) out1[n0 + tt] = (float)sel;
    }
}

extern "C" void kernel_launch(void* const* d_in, const int* in_sizes, int n_in,
                              void* d_out, int out_size, void* d_ws, size_t ws_size,
                              hipStream_t stream) {
    const float* inputs = (const float*)d_in[0];   // (3,8,10,512,512)
    const float* w1     = (const float*)d_in[1];   // (30,256)
    const float* b1     = (const float*)d_in[2];   // (256,)
    const float* w2     = (const float*)d_in[3];   // (256,3)
    const float* b2     = (const float*)d_in[4];   // (3,)

    float* out0 = (float*)d_out;           // (8,10,512,512)
    float* out1 = out0 + BCHW;             // (8,512,512) selections as float

    mlp_select_mfma<<<NBLOCKS, 512, 0, stream>>>(
        inputs, w1, b1, w2, b2, out0, out1);
}

// Round 8
// 488.804 us; speedup vs baseline: 1.0323x; 1.0103x over previous
//
#include <hip/hip_runtime.h>

// (E,B,C,H,W) = (3,8,10,512,512), HIDDEN=256
#define HWQ   262144      // H*W
#define CHW   2621440     // C*H*W
#define BCHW  20971520    // B*C*H*W
#define NTOT  2097152     // B*H*W

#define NBLOCKS   768     // 3 resident blocks per CU, exactly (r5-proven shape)
#define NBLKITER  8192    // NTOT / 256 tokens-per-block-iter
#define BITERS    11      // ceil(8192/768); guard g < NBLKITER

typedef __attribute__((ext_vector_type(8))) short short8;  // 8 bf16 (4 VGPRs)
typedef __attribute__((ext_vector_type(4))) float f32x4;
typedef __attribute__((ext_vector_type(2))) float v2f;     // packed fp32 pair

union Frag { uint u[4]; uint4 u4; short8 s; };   // 16B type-pun (union: OK in HIP)

// f32 -> bf16 (RNE), pure C bit-trick. NO inline asm / dpp / 1024-thr blocks —
// every failed round (r1/r2/r6/r7) introduced exactly one exotic construct;
// this kernel sticks to the r3/r5-proven set.
__device__ __forceinline__ uint bf16w(float x) {
    const uint u = __float_as_uint(x);
    return (u + 0x7FFFu + ((u >> 16) & 1u)) >> 16;   // bf16 in low 16 bits
}

// 3-limb split of an f32 pair into packed bf16 words (lo16 = a, hi16 = b).
// v = hi + mid + lo with residual ~2^-25 * |v| (hi/mid subtractions exact).
__device__ __forceinline__ void split_pair(float a, float b,
                                           uint& h, uint& m, uint& l) {
    const uint ha = bf16w(a), hb = bf16w(b);
    h = ha | (hb << 16);
    const float fa = __uint_as_float(ha << 16);
    const float fb = __uint_as_float(hb << 16);
    const float ra = a - fa, rb = b - fb;
    const uint ma = bf16w(ra), mb = bf16w(rb);
    m = ma | (mb << 16);
    const float ga = __uint_as_float(ma << 16);
    const float gb = __uint_as_float(mb << 16);
    l = bf16w(ra - ga) | (bf16w(rb - gb) << 16);
}

// Exact r5 structure + ONE change: the 16-load scattered gather for iter n+1
// is ISSUED before iter n's MFMA phase (software pipeline). The ~900-cyc HBM
// latency hides under ~4500 cyc of MFMA+reduce+write; the waitcnt lands at the
// register rotate at the loop tail. Geometry, numerics, op order = r5 (passed,
// absmax 0.0). LDS = 49,152 + 3,072 = 52,224 B -> 3 blocks/CU.
__global__ __launch_bounds__(512)
void mlp_select_mfma(const float* __restrict__ inputs,
                     const float* __restrict__ w1,
                     const float* __restrict__ b1,
                     const float* __restrict__ w2,
                     const float* __restrict__ b2,
                     float* __restrict__ out0,
                     float* __restrict__ out1) {
    __shared__ uint4 Bfrag[16 * 3 * 64];   // 49,152 B: [ht][limb][lane] 16B frags
    __shared__ float W2s[768];             // w2 copy (256x3)

    const int tid = threadIdx.x;

    // ---- one-time staging: w1/b1 -> limb B-fragments; w2 -> LDS ----
    for (int idx = tid; idx < 16 * 64; idx += 512) {
        const int ht = idx >> 6, ln = idx & 63;
        const int col = (ht << 4) | (ln & 15);     // hidden unit (B col = lane&15)
        const int kbs = (ln >> 4) << 3;            // k-group base (same conv as A)
        Frag fh, fm, fl;
        #pragma unroll
        for (int jj = 0; jj < 4; ++jj) {
            const int k0 = kbs + 2 * jj, k1 = k0 + 1;
            const float a = (k0 < 30) ? w1[k0 * 256 + col]
                                      : ((k0 == 30) ? b1[col] : 0.f);
            const float b = (k1 < 30) ? w1[k1 * 256 + col]
                                      : ((k1 == 30) ? b1[col] : 0.f);
            split_pair(a, b, fh.u[jj], fm.u[jj], fl.u[jj]);
        }
        const int base = ht * 3 * 64 + ln;
        Bfrag[base]       = fh.u4;
        Bfrag[base + 64]  = fm.u4;
        Bfrag[base + 128] = fl.u4;
    }
    for (int i = tid; i < 768; i += 512) W2s[i] = w2[i];
    __syncthreads();

    const int lane = tid & 63;
    const int wid  = tid >> 6;
    const int l15  = lane & 15;
    const int lg   = lane >> 4;
    const int kb   = lg << 3;

    // per-lane byte offsets of the 8 k-planes this lane loads (A-frag k-slice)
    uint koff[8];
    #pragma unroll
    for (int j = 0; j < 8; ++j) {
        const int k = kb + j;
        const int e = (k >= 20) ? 2 : ((k >= 10) ? 1 : 0);
        const int c = k - e * 10;
        koff[j] = (k < 30) ? (uint)((e * BCHW + c * HWQ) * 4) : 0u;  // k>=30: dummy
    }
    // b2 folded into acc init: 16 butterfly lanes each contribute b2/16 (exact
    // pow2 scale; xor-reduce sums back to exactly one b2).
    const float i20 = b2[0] * 0.0625f, i21 = b2[1] * 0.0625f, i22 = b2[2] * 0.0625f;
    const char* ib = (const char*)inputs;
    char* ob = (char*)out0;
    const int bid = (int)blockIdx.x;

    // ---- prologue: gather iter 0 (it=0 always valid: bid < 768 < 8192) ----
    uint sb;
    {
        const int n0 = bid * 256 + wid * 32;
        sb = (uint)((n0 >> 18) * CHW + (n0 & (HWQ - 1))) * 4u;
    }
    float xv[16];
    #pragma unroll
    for (int t = 0; t < 2; ++t) {
        const uint vb = sb + (uint)((t * 16 + l15) * 4);
        #pragma unroll
        for (int j = 0; j < 8; ++j)
            xv[t * 8 + j] = *(const float*)(ib + (size_t)(vb + koff[j]));
    }

    #pragma unroll 1
    for (int it = 0; it < BITERS; ++it) {
        const int g = it * NBLOCKS + bid;               // global block-iter
        if (g >= NBLKITER) break;
        const int n0 = g * 256 + wid * 32;              // wave's 32 tokens
        // invariant: sb corresponds to n0

        // ---- split current gather -> A fragments for 2 16-token tiles ----
        short8 Ah[2], Am[2], Al[2];
        #pragma unroll
        for (int t = 0; t < 2; ++t) {
            float a6 = xv[t * 8 + 6], a7 = xv[t * 8 + 7];
            if (kb == 24) { a6 = 1.f; a7 = 0.f; }  // k=30 -> bias 1.0, k=31 -> 0
            Frag ch_, cm_, cl_;
            split_pair(xv[t * 8 + 0], xv[t * 8 + 1], ch_.u[0], cm_.u[0], cl_.u[0]);
            split_pair(xv[t * 8 + 2], xv[t * 8 + 3], ch_.u[1], cm_.u[1], cl_.u[1]);
            split_pair(xv[t * 8 + 4], xv[t * 8 + 5], ch_.u[2], cm_.u[2], cl_.u[2]);
            split_pair(a6, a7, ch_.u[3], cm_.u[3], cl_.u[3]);
            Ah[t] = ch_.s; Am[t] = cm_.s; Al[t] = cl_.s;
        }

        // ---- issue next-iter prefetch NOW; consumed after the MFMA phase ----
        const int gn = g + NBLOCKS;
        uint sbn = sb;                      // invalid next -> reload same (safe)
        if (gn < NBLKITER) {
            const int nn = gn * 256 + wid * 32;
            sbn = (uint)((nn >> 18) * CHW + (nn & (HWQ - 1))) * 4u;
        }
        float xn[16];
        #pragma unroll
        for (int t = 0; t < 2; ++t) {
            const uint vb = sbn + (uint)((t * 16 + l15) * 4);
            #pragma unroll
            for (int j = 0; j < 8; ++j)
                xn[t * 8 + j] = *(const float*)(ib + (size_t)(vb + koff[j]));
        }

        // packed logit accumulators: element .x = token-tile t=0, .y = t=1
        v2f lacc[4][3];
        #pragma unroll
        for (int r = 0; r < 4; ++r) {
            lacc[r][0] = (v2f){i20, i20};
            lacc[r][1] = (v2f){i21, i21};
            lacc[r][2] = (v2f){i22, i22};
        }

        // ---- 16 hidden-tiles: 6 limb-product MFMAs each (small terms first),
        //      then packed relu + w2-fma epilogue ----
        #pragma unroll 4
        for (int ht = 0; ht < 16; ++ht) {
            const uint4* bp = &Bfrag[ht * 3 * 64 + lane];
            Frag bh, bm, bl;
            bh.u4 = bp[0]; bm.u4 = bp[64]; bl.u4 = bp[128];
            const int wcol = ((ht << 4) | l15) * 3;
            const float w20 = W2s[wcol], w21 = W2s[wcol + 1], w22 = W2s[wcol + 2];
            f32x4 Dt[2];
            #pragma unroll
            for (int t = 0; t < 2; ++t) {
                f32x4 D = {0.f, 0.f, 0.f, 0.f};
                D = __builtin_amdgcn_mfma_f32_16x16x32_bf16(Al[t], bh.s, D, 0, 0, 0);
                D = __builtin_amdgcn_mfma_f32_16x16x32_bf16(Ah[t], bl.s, D, 0, 0, 0);
                D = __builtin_amdgcn_mfma_f32_16x16x32_bf16(Am[t], bm.s, D, 0, 0, 0);
                D = __builtin_amdgcn_mfma_f32_16x16x32_bf16(Am[t], bh.s, D, 0, 0, 0);
                D = __builtin_amdgcn_mfma_f32_16x16x32_bf16(Ah[t], bm.s, D, 0, 0, 0);
                D = __builtin_amdgcn_mfma_f32_16x16x32_bf16(Ah[t], bh.s, D, 0, 0, 0);
                Dt[t] = D;
            }
            #pragma unroll
            for (int r = 0; r < 4; ++r) {     // D: token = lg*4+r (per tile)
                v2f h2 = {Dt[0][r], Dt[1][r]};
                h2 = __builtin_elementwise_max(h2, (v2f){0.f, 0.f});
                lacc[r][0] = __builtin_elementwise_fma(h2, (v2f){w20, w20}, lacc[r][0]);
                lacc[r][1] = __builtin_elementwise_fma(h2, (v2f){w21, w21}, lacc[r][1]);
                lacc[r][2] = __builtin_elementwise_fma(h2, (v2f){w22, w22}, lacc[r][2]);
            }
        }

        // ---- butterfly-reduce over the 16 hidden-lanes: ALL lanes get sums ----
        #pragma unroll
        for (int r = 0; r < 4; ++r)
            #pragma unroll
            for (int e = 0; e < 3; ++e) {
                v2f v = lacc[r][e];
                #pragma unroll
                for (int s = 1; s <= 8; s <<= 1) {
                    v2f o;
                    o.x = __shfl_xor(v.x, s);
                    o.y = __shfl_xor(v.y, s);
                    v += o;                                  // v_pk_add_f32
                }
                lacc[r][e] = v;
            }

        // ---- per-lane argmax of this lg-group's 8 tokens, 2-bit packed ----
        uint selpk = 0;
        #pragma unroll
        for (int t = 0; t < 2; ++t)
            #pragma unroll
            for (int r = 0; r < 4; ++r) {
                const float L0 = (t == 0) ? lacc[r][0].x : lacc[r][0].y;
                const float L1 = (t == 0) ? lacc[r][1].x : lacc[r][1].y;
                const float L2 = (t == 0) ? lacc[r][2].x : lacc[r][2].y;
                int sel = 0; float best = L0;
                if (L1 > best) { best = L1; sel = 1; }
                if (L2 > best) { sel = 2; }
                selpk |= (uint)sel << ((t * 4 + r) * 2);
            }

        // route: token tt = t<<4 | lg'<<2 | r lives in lanes with lg = lg'
        const int tt  = lane & 31;
        const int src = (((tt >> 2) & 3) << 4) | l15;        // same l15: permutation
        const uint pk = (uint)__shfl((int)selpk, src);
        const int sel = (int)((pk >> ((((tt >> 4) << 2) | (tt & 3)) * 2)) & 3u);

        // ---- gather-write selected expert's 10 planes (lines L2-hot) ----
        const uint obase = sb + (uint)(tt * 4);
        const uint ioff  = obase + (uint)sel * (uint)(BCHW * 4);
        const int chalf  = lane >> 5;          // lanes 0-31: c=0..4, 32-63: c=5..9
        #pragma unroll
        for (int cc = 0; cc < 5; ++cc) {
            const uint cofs = (uint)((chalf * 5 + cc) * (HWQ * 4));
            const float v = *(const float*)(ib + (size_t)(ioff + cofs));
            *(float*)(ob + (size_t)(obase + cofs)) = v;
        }
        if (lane < 32) out1[n0 + tt] = (float)sel;

        // ---- rotate pipeline: waitcnt for xn lands here, ~4500 cyc after issue
        sb = sbn;
        #pragma unroll
        for (int q = 0; q < 16; ++q) xv[q] = xn[q];
    }
}

extern "C" void kernel_launch(void* const* d_in, const int* in_sizes, int n_in,
                              void* d_out, int out_size, void* d_ws, size_t ws_size,
                              hipStream_t stream) {
    const float* inputs = (const float*)d_in[0];   // (3,8,10,512,512)
    const float* w1     = (const float*)d_in[1];   // (30,256)
    const float* b1     = (const float*)d_in[2];   // (256,)
    const float* w2     = (const float*)d_in[3];   // (256,3)
    const float* b2     = (const float*)d_in[4];   // (3,)

    float* out0 = (float*)d_out;           // (8,10,512,512)
    float* out1 = out0 + BCHW;             // (8,512,512) selections as float

    mlp_select_mfma<<<NBLOCKS, 512, 0, stream>>>(
        inputs, w1, b1, w2, b2, out0, out1);
}